// Round 1
// baseline (512.967 us; speedup 1.0000x reference)
//
#include <hip/hip_runtime.h>
#include <hip/hip_bf16.h>

#define NN 100000
#define NE 1600000
#define SCAN_BS 512
#define SCAN_NB 196   // ceil(100000/512)

typedef __attribute__((ext_vector_type(8))) short bf16x8;
typedef __attribute__((ext_vector_type(4))) float f32x4;

__device__ __forceinline__ unsigned short f2bf(float x) {
    unsigned u = __float_as_uint(x);
    return (unsigned short)((u + 0x7fffu + ((u >> 16) & 1u)) >> 16);
}

// ---------------- cast x (f32) -> bf16 ----------------
__global__ void cast_x(const float* __restrict__ x, unsigned short* __restrict__ h, int n) {
    int i = (blockIdx.x * blockDim.x + threadIdx.x) * 4;
    if (i >= n) return;
    float4 v = *(const float4*)(x + i);
    unsigned short o0 = f2bf(v.x), o1 = f2bf(v.y), o2 = f2bf(v.z), o3 = f2bf(v.w);
    unsigned out0 = ((unsigned)o1 << 16) | o0;
    unsigned out1 = ((unsigned)o3 << 16) | o2;
    *(uint2*)(h + i) = make_uint2(out0, out1);
}

// ---------------- degree histogram ----------------
__global__ void hist_deg(const int* __restrict__ dst, int* __restrict__ deg) {
    int e = blockIdx.x * blockDim.x + threadIdx.x;
    if (e < NE) atomicAdd(&deg[dst[e]], 1);
}

// ---------------- scan: block partial sums ----------------
__global__ void scan_partial(const int* __restrict__ deg, int* __restrict__ bsum) {
    __shared__ int s[SCAN_BS];
    int i = blockIdx.x * SCAN_BS + threadIdx.x;
    s[threadIdx.x] = (i < NN) ? deg[i] : 0;
    __syncthreads();
    for (int off = SCAN_BS / 2; off > 0; off >>= 1) {
        if (threadIdx.x < off) s[threadIdx.x] += s[threadIdx.x + off];
        __syncthreads();
    }
    if (threadIdx.x == 0) bsum[blockIdx.x] = s[0];
}

// ---------------- scan of block sums (exclusive, serial; tiny) ----------------
__global__ void scan_bsum(int* __restrict__ bsum, int nb) {
    if (threadIdx.x == 0 && blockIdx.x == 0) {
        int acc = 0;
        for (int i = 0; i < nb; ++i) { int v = bsum[i]; bsum[i] = acc; acc += v; }
    }
}

// ---------------- final scan -> row_ptr (exclusive) + inv_deg ----------------
__global__ void scan_final(const int* __restrict__ deg, const int* __restrict__ bsum,
                           int* __restrict__ row_ptr, float* __restrict__ inv_deg) {
    __shared__ int s[SCAN_BS];
    int i = blockIdx.x * SCAN_BS + threadIdx.x;
    int v = (i < NN) ? deg[i] : 0;
    s[threadIdx.x] = v;
    __syncthreads();
    for (int off = 1; off < SCAN_BS; off <<= 1) {
        int t = (threadIdx.x >= off) ? s[threadIdx.x - off] : 0;
        __syncthreads();
        s[threadIdx.x] += t;
        __syncthreads();
    }
    if (i < NN) {
        int incl = s[threadIdx.x];
        row_ptr[i] = bsum[blockIdx.x] + incl - v;
        inv_deg[i] = 1.0f / (float)max(v, 1);
    }
    if (i == 0) row_ptr[NN] = NE;
}

// ---------------- fill CSR buckets ----------------
__global__ void fill_csr(const int* __restrict__ src, const int* __restrict__ dst,
                         const int* __restrict__ row_ptr, int* __restrict__ cursor,
                         int* __restrict__ csr) {
    int e = blockIdx.x * blockDim.x + threadIdx.x;
    if (e < NE) {
        int d = dst[e];
        int p = atomicAdd(&cursor[d], 1);
        csr[row_ptr[d] + p] = src[e];
    }
}

// ---------------- pack [W_self; W_neigh] (f32) into MFMA B-fragment bf16 layout ----------------
// layout: wpack[((kstep*NF + nf)*64 + lane)*8 + j], k = kstep*32 + (lane>>4)*8 + j, n = nf*16 + (lane&15)
__global__ void pack_w(const float* __restrict__ Wself, const float* __restrict__ Wneigh,
                       unsigned short* __restrict__ wpack, int Ncols, int NF) {
    int idx = blockIdx.x * blockDim.x + threadIdx.x;
    int total = 8 * NF * 64 * 8;
    if (idx >= total) return;
    int j = idx & 7;
    int lane = (idx >> 3) & 63;
    int fid = idx >> 9;          // kstep*NF + nf
    int nf = fid % NF;
    int kstep = fid / NF;
    int k = kstep * 32 + (lane >> 4) * 8 + j;
    int n = nf * 16 + (lane & 15);
    float v = 0.f;
    if (n < Ncols) v = (k < 128) ? Wself[k * Ncols + n] : Wneigh[(k - 128) * Ncols + n];
    wpack[idx] = f2bf(v);
}

// ---------------- pull-mode mean aggregation: one wave per node ----------------
__global__ void aggregate(const unsigned* __restrict__ h32, const int* __restrict__ csr,
                          const int* __restrict__ row_ptr, const float* __restrict__ inv_deg,
                          unsigned* __restrict__ agg32) {
    int lane = threadIdx.x & 63;
    int node = blockIdx.x * (blockDim.x >> 6) + (threadIdx.x >> 6);
    if (node >= NN) return;
    int beg = row_ptr[node], end = row_ptr[node + 1];
    float a0 = 0.f, a1 = 0.f;
    int e = beg;
    for (; e + 3 < end; e += 4) {
        int s0 = csr[e], s1 = csr[e + 1], s2 = csr[e + 2], s3 = csr[e + 3];
        unsigned v0 = h32[s0 * 64 + lane];
        unsigned v1 = h32[s1 * 64 + lane];
        unsigned v2 = h32[s2 * 64 + lane];
        unsigned v3 = h32[s3 * 64 + lane];
        a0 += __uint_as_float(v0 << 16) + __uint_as_float(v1 << 16)
            + __uint_as_float(v2 << 16) + __uint_as_float(v3 << 16);
        a1 += __uint_as_float(v0 & 0xffff0000u) + __uint_as_float(v1 & 0xffff0000u)
            + __uint_as_float(v2 & 0xffff0000u) + __uint_as_float(v3 & 0xffff0000u);
    }
    for (; e < end; ++e) {
        unsigned v = h32[csr[e] * 64 + lane];
        a0 += __uint_as_float(v << 16);
        a1 += __uint_as_float(v & 0xffff0000u);
    }
    float inv = inv_deg[node];
    a0 *= inv; a1 *= inv;
    agg32[node * 64 + lane] = ((unsigned)f2bf(a1) << 16) | f2bf(a0);
}

// ---------------- fused GEMM: out = h@Wself + agg@Wneigh (K=256 via packed W) ----------------
// block = 256 thr = 4 waves; wave handles 16 rows x (NF*16) cols via 16x16x32 MFMA
template <int NF, bool LAST>
__global__ __launch_bounds__(256) void gemm_k(const unsigned short* __restrict__ hA,
                                              const unsigned short* __restrict__ hAgg,
                                              const unsigned short* __restrict__ wpack,
                                              unsigned short* __restrict__ hOut,
                                              float* __restrict__ fOut) {
    int lane = threadIdx.x & 63;
    int wave = threadIdx.x >> 6;
    int aRow = blockIdx.x * 64 + wave * 16 + (lane & 15);
    int kgrp = (lane >> 4) * 8;

    f32x4 acc[NF];
#pragma unroll
    for (int f = 0; f < NF; ++f)
#pragma unroll
        for (int r = 0; r < 4; ++r) acc[f][r] = 0.f;

    bool inb = (aRow < NN);
#pragma unroll
    for (int half = 0; half < 2; ++half) {
        const unsigned short* A = half ? hAgg : hA;
#pragma unroll
        for (int ks = 0; ks < 4; ++ks) {
            bf16x8 afrag;
            if (inb) {
                afrag = *(const bf16x8*)(A + aRow * 128 + ks * 32 + kgrp);
            } else {
#pragma unroll
                for (int j = 0; j < 8; ++j) afrag[j] = 0;
            }
            int kstep = half * 4 + ks;
#pragma unroll
            for (int nf = 0; nf < NF; ++nf) {
                bf16x8 b = *(const bf16x8*)(wpack + (((kstep * NF + nf) * 64) + lane) * 8);
                acc[nf] = __builtin_amdgcn_mfma_f32_16x16x32_bf16(afrag, b, acc[nf], 0, 0, 0);
            }
        }
    }

    int col0 = lane & 15;
    int rBase = blockIdx.x * 64 + wave * 16 + (lane >> 4) * 4;
#pragma unroll
    for (int nf = 0; nf < NF; ++nf) {
        int col = nf * 16 + col0;
        if (LAST) {
            if (col < 47) {
#pragma unroll
                for (int r = 0; r < 4; ++r) {
                    int row = rBase + r;
                    if (row < NN) fOut[row * 47 + col] = acc[nf][r];
                }
            }
        } else {
#pragma unroll
            for (int r = 0; r < 4; ++r) {
                int row = rBase + r;
                if (row < NN) hOut[row * 128 + col] = f2bf(fmaxf(acc[nf][r], 0.f));
            }
        }
    }
}

static inline size_t alignup(size_t x) { return (x + 255) & ~(size_t)255; }

extern "C" void kernel_launch(void* const* d_in, const int* in_sizes, int n_in,
                              void* d_out, int out_size, void* d_ws, size_t ws_size,
                              hipStream_t stream) {
    const float* x   = (const float*)d_in[0];
    const float* Ws0 = (const float*)d_in[1];
    const float* Wn0 = (const float*)d_in[2];
    const float* Ws1 = (const float*)d_in[3];
    const float* Wn1 = (const float*)d_in[4];
    const float* Ws2 = (const float*)d_in[5];
    const float* Wn2 = (const float*)d_in[6];
    const int* src   = (const int*)d_in[7];
    const int* dst   = (const int*)d_in[8];
    float* out = (float*)d_out;

    char* w = (char*)d_ws;
    size_t off = 0;
    int* row_ptr   = (int*)(w + off);   off += alignup((NN + 1) * 4);
    int* deg       = (int*)(w + off);   off += alignup(NN * 4);
    int* cursor    = (int*)(w + off);   off += alignup(NN * 4);
    int* bsum      = (int*)(w + off);   off += alignup(SCAN_NB * 4);
    float* inv_deg = (float*)(w + off); off += alignup(NN * 4);
    int* csr       = (int*)(w + off);   off += alignup((size_t)NE * 4);
    unsigned short* wp0 = (unsigned short*)(w + off); off += alignup(8 * 8 * 64 * 8 * 2);
    unsigned short* wp1 = (unsigned short*)(w + off); off += alignup(8 * 8 * 64 * 8 * 2);
    unsigned short* wp2 = (unsigned short*)(w + off); off += alignup(8 * 3 * 64 * 8 * 2);
    unsigned short* hA  = (unsigned short*)(w + off); off += alignup((size_t)NN * 128 * 2);
    unsigned short* hB  = (unsigned short*)(w + off); off += alignup((size_t)NN * 128 * 2);
    unsigned short* agg = (unsigned short*)(w + off); off += alignup((size_t)NN * 128 * 2);

    hipMemsetAsync(deg, 0, NN * 4, stream);
    hipMemsetAsync(cursor, 0, NN * 4, stream);

    cast_x<<<dim3((NN * 128 / 4 + 255) / 256), dim3(256), 0, stream>>>(x, hA, NN * 128);
    hist_deg<<<dim3(NE / 256), dim3(256), 0, stream>>>(dst, deg);
    scan_partial<<<dim3(SCAN_NB), dim3(SCAN_BS), 0, stream>>>(deg, bsum);
    scan_bsum<<<dim3(1), dim3(64), 0, stream>>>(bsum, SCAN_NB);
    scan_final<<<dim3(SCAN_NB), dim3(SCAN_BS), 0, stream>>>(deg, bsum, row_ptr, inv_deg);
    fill_csr<<<dim3(NE / 256), dim3(256), 0, stream>>>(src, dst, row_ptr, cursor, csr);

    pack_w<<<dim3((8 * 8 * 64 * 8 + 255) / 256), dim3(256), 0, stream>>>(Ws0, Wn0, wp0, 128, 8);
    pack_w<<<dim3((8 * 8 * 64 * 8 + 255) / 256), dim3(256), 0, stream>>>(Ws1, Wn1, wp1, 128, 8);
    pack_w<<<dim3((8 * 3 * 64 * 8 + 255) / 256), dim3(256), 0, stream>>>(Ws2, Wn2, wp2, 47, 3);

    const int gemmGrid = (NN + 63) / 64;

    // layer 0
    aggregate<<<dim3(NN / 4), dim3(256), 0, stream>>>((const unsigned*)hA, csr, row_ptr, inv_deg, (unsigned*)agg);
    gemm_k<8, false><<<dim3(gemmGrid), dim3(256), 0, stream>>>(hA, agg, wp0, hB, nullptr);
    // layer 1
    aggregate<<<dim3(NN / 4), dim3(256), 0, stream>>>((const unsigned*)hB, csr, row_ptr, inv_deg, (unsigned*)agg);
    gemm_k<8, false><<<dim3(gemmGrid), dim3(256), 0, stream>>>(hB, agg, wp1, hA, nullptr);
    // layer 2
    aggregate<<<dim3(NN / 4), dim3(256), 0, stream>>>((const unsigned*)hA, csr, row_ptr, inv_deg, (unsigned*)agg);
    gemm_k<3, true><<<dim3(gemmGrid), dim3(256), 0, stream>>>(hA, agg, wp2, nullptr, out);
}

// Round 2
// 488.317 us; speedup vs baseline: 1.0505x; 1.0505x over previous
//
#include <hip/hip_runtime.h>
#include <hip/hip_bf16.h>

#define NN 100000
#define NE 1600000
#define SCAN_BS 512
#define SCAN_NB 196   // ceil(100000/512)
#define NBUCK 1563    // ceil(100000/64)

typedef __attribute__((ext_vector_type(8))) short bf16x8;
typedef __attribute__((ext_vector_type(4))) float f32x4;

__device__ __forceinline__ unsigned short f2bf(float x) {
    unsigned u = __float_as_uint(x);
    return (unsigned short)((u + 0x7fffu + ((u >> 16) & 1u)) >> 16);
}

// ---------------- cast x (f32) -> bf16 ----------------
__global__ void cast_x(const float* __restrict__ x, unsigned short* __restrict__ h, int n) {
    int i = (blockIdx.x * blockDim.x + threadIdx.x) * 4;
    if (i >= n) return;
    float4 v = *(const float4*)(x + i);
    unsigned short o0 = f2bf(v.x), o1 = f2bf(v.y), o2 = f2bf(v.z), o3 = f2bf(v.w);
    unsigned out0 = ((unsigned)o1 << 16) | o0;
    unsigned out1 = ((unsigned)o3 << 16) | o2;
    *(uint2*)(h + i) = make_uint2(out0, out1);
}

// ---------------- degree histogram ----------------
__global__ void hist_deg(const int* __restrict__ dst, int* __restrict__ deg) {
    int e = blockIdx.x * blockDim.x + threadIdx.x;
    if (e < NE) atomicAdd(&deg[dst[e]], 1);
}

// ---------------- scan: block partial sums ----------------
__global__ void scan_partial(const int* __restrict__ deg, int* __restrict__ bsum) {
    __shared__ int s[SCAN_BS];
    int i = blockIdx.x * SCAN_BS + threadIdx.x;
    s[threadIdx.x] = (i < NN) ? deg[i] : 0;
    __syncthreads();
    for (int off = SCAN_BS / 2; off > 0; off >>= 1) {
        if (threadIdx.x < off) s[threadIdx.x] += s[threadIdx.x + off];
        __syncthreads();
    }
    if (threadIdx.x == 0) bsum[blockIdx.x] = s[0];
}

// ---------------- exclusive scan of block sums (one block, LDS Hillis-Steele) ----------------
__global__ void scan_bsum(int* __restrict__ bsum, int nb) {
    __shared__ int s[256];
    int t = threadIdx.x;
    int orig = (t < nb) ? bsum[t] : 0;
    s[t] = orig;
    __syncthreads();
    for (int off = 1; off < 256; off <<= 1) {
        int v = (t >= off) ? s[t - off] : 0;
        __syncthreads();
        s[t] += v;
        __syncthreads();
    }
    if (t < nb) bsum[t] = s[t] - orig;
}

// ---------------- final scan -> row_ptr (exclusive) + inv_deg ----------------
__global__ void scan_final(const int* __restrict__ deg, const int* __restrict__ bsum,
                           int* __restrict__ row_ptr, float* __restrict__ inv_deg) {
    __shared__ int s[SCAN_BS];
    int i = blockIdx.x * SCAN_BS + threadIdx.x;
    int v = (i < NN) ? deg[i] : 0;
    s[threadIdx.x] = v;
    __syncthreads();
    for (int off = 1; off < SCAN_BS; off <<= 1) {
        int t = (threadIdx.x >= off) ? s[threadIdx.x - off] : 0;
        __syncthreads();
        s[threadIdx.x] += t;
        __syncthreads();
    }
    if (i < NN) {
        int incl = s[threadIdx.x];
        row_ptr[i] = bsum[blockIdx.x] + incl - v;
        inv_deg[i] = 1.0f / (float)max(v, 1);
    }
    if (i == 0) row_ptr[NN] = NE;
}

// ---------------- bucket bases: bb[b] = row_ptr[min(64b, NN)] ----------------
__global__ void bb_fill(const int* __restrict__ row_ptr, int* __restrict__ bb) {
    int b = blockIdx.x * blockDim.x + threadIdx.x;
    if (b <= NBUCK) bb[b] = row_ptr[min(b * 64, NN)];
}

// ---------------- pass B: scatter (src,dst) pairs into contiguous bucket regions ----------------
__global__ void pair_scatter(const int* __restrict__ src, const int* __restrict__ dst,
                             const int* __restrict__ bb, int* __restrict__ cur,
                             uint2* __restrict__ pairs) {
    int e = blockIdx.x * blockDim.x + threadIdx.x;
    if (e < NE) {
        int s = src[e], d = dst[e];
        int b = d >> 6;
        int p = atomicAdd(&cur[b * 16], 1);   // 64B-padded cursors
        pairs[bb[b] + p] = make_uint2((unsigned)s, (unsigned)d);
    }
}

// ---------------- pass C: place within bucket -> final csr (contiguous region per block) ----------
__global__ __launch_bounds__(256) void bucket_place(const uint2* __restrict__ pairs,
                                                    const int* __restrict__ row_ptr,
                                                    const int* __restrict__ bb,
                                                    int* __restrict__ csr) {
    __shared__ int curs[64];
    int b = blockIdx.x;
    int base = b * 64;
    if (threadIdx.x < 64) {
        int node = min(base + (int)threadIdx.x, NN);
        curs[threadIdx.x] = row_ptr[node];   // absolute csr position
    }
    __syncthreads();
    int beg = bb[b], end = bb[b + 1];
    for (int i = beg + (int)threadIdx.x; i < end; i += 256) {
        uint2 p = pairs[i];
        int pos = atomicAdd(&curs[p.y - (unsigned)base], 1);
        csr[pos] = (int)p.x;
    }
}

// ---------------- pack [W_self; W_neigh] (f32) into MFMA B-fragment bf16 layout ----------------
__global__ void pack_w(const float* __restrict__ Wself, const float* __restrict__ Wneigh,
                       unsigned short* __restrict__ wpack, int Ncols, int NF) {
    int idx = blockIdx.x * blockDim.x + threadIdx.x;
    int total = 8 * NF * 64 * 8;
    if (idx >= total) return;
    int j = idx & 7;
    int lane = (idx >> 3) & 63;
    int fid = idx >> 9;          // kstep*NF + nf
    int nf = fid % NF;
    int kstep = fid / NF;
    int k = kstep * 32 + (lane >> 4) * 8 + j;
    int n = nf * 16 + (lane & 15);
    float v = 0.f;
    if (n < Ncols) v = (k < 128) ? Wself[k * Ncols + n] : Wneigh[(k - 128) * Ncols + n];
    wpack[idx] = f2bf(v);
}

// ---------------- pull-mode mean aggregation: one wave per node ----------------
__global__ void aggregate(const unsigned* __restrict__ h32, const int* __restrict__ csr,
                          const int* __restrict__ row_ptr, const float* __restrict__ inv_deg,
                          unsigned* __restrict__ agg32) {
    int lane = threadIdx.x & 63;
    int node = blockIdx.x * (blockDim.x >> 6) + (threadIdx.x >> 6);
    if (node >= NN) return;
    int beg = row_ptr[node], end = row_ptr[node + 1];
    float a0 = 0.f, a1 = 0.f;
    int e = beg;
    for (; e + 3 < end; e += 4) {
        int s0 = csr[e], s1 = csr[e + 1], s2 = csr[e + 2], s3 = csr[e + 3];
        unsigned v0 = h32[s0 * 64 + lane];
        unsigned v1 = h32[s1 * 64 + lane];
        unsigned v2 = h32[s2 * 64 + lane];
        unsigned v3 = h32[s3 * 64 + lane];
        a0 += __uint_as_float(v0 << 16) + __uint_as_float(v1 << 16)
            + __uint_as_float(v2 << 16) + __uint_as_float(v3 << 16);
        a1 += __uint_as_float(v0 & 0xffff0000u) + __uint_as_float(v1 & 0xffff0000u)
            + __uint_as_float(v2 & 0xffff0000u) + __uint_as_float(v3 & 0xffff0000u);
    }
    for (; e < end; ++e) {
        unsigned v = h32[csr[e] * 64 + lane];
        a0 += __uint_as_float(v << 16);
        a1 += __uint_as_float(v & 0xffff0000u);
    }
    float inv = inv_deg[node];
    a0 *= inv; a1 *= inv;
    agg32[node * 64 + lane] = ((unsigned)f2bf(a1) << 16) | f2bf(a0);
}

// ---------------- fused GEMM: out = h@Wself + agg@Wneigh (K=256 via packed W) ----------------
template <int NF, bool LAST>
__global__ __launch_bounds__(256) void gemm_k(const unsigned short* __restrict__ hA,
                                              const unsigned short* __restrict__ hAgg,
                                              const unsigned short* __restrict__ wpack,
                                              unsigned short* __restrict__ hOut,
                                              float* __restrict__ fOut) {
    int lane = threadIdx.x & 63;
    int wave = threadIdx.x >> 6;
    int aRow = blockIdx.x * 64 + wave * 16 + (lane & 15);
    int kgrp = (lane >> 4) * 8;

    f32x4 acc[NF];
#pragma unroll
    for (int f = 0; f < NF; ++f)
#pragma unroll
        for (int r = 0; r < 4; ++r) acc[f][r] = 0.f;

    bool inb = (aRow < NN);
#pragma unroll
    for (int half = 0; half < 2; ++half) {
        const unsigned short* A = half ? hAgg : hA;
#pragma unroll
        for (int ks = 0; ks < 4; ++ks) {
            bf16x8 afrag;
            if (inb) {
                afrag = *(const bf16x8*)(A + aRow * 128 + ks * 32 + kgrp);
            } else {
#pragma unroll
                for (int j = 0; j < 8; ++j) afrag[j] = 0;
            }
            int kstep = half * 4 + ks;
#pragma unroll
            for (int nf = 0; nf < NF; ++nf) {
                bf16x8 b = *(const bf16x8*)(wpack + (((kstep * NF + nf) * 64) + lane) * 8);
                acc[nf] = __builtin_amdgcn_mfma_f32_16x16x32_bf16(afrag, b, acc[nf], 0, 0, 0);
            }
        }
    }

    int col0 = lane & 15;
    int rBase = blockIdx.x * 64 + wave * 16 + (lane >> 4) * 4;
#pragma unroll
    for (int nf = 0; nf < NF; ++nf) {
        int col = nf * 16 + col0;
        if (LAST) {
            if (col < 47) {
#pragma unroll
                for (int r = 0; r < 4; ++r) {
                    int row = rBase + r;
                    if (row < NN) fOut[row * 47 + col] = acc[nf][r];
                }
            }
        } else {
#pragma unroll
            for (int r = 0; r < 4; ++r) {
                int row = rBase + r;
                if (row < NN) hOut[row * 128 + col] = f2bf(fmaxf(acc[nf][r], 0.f));
            }
        }
    }
}

static inline size_t alignup(size_t x) { return (x + 255) & ~(size_t)255; }

extern "C" void kernel_launch(void* const* d_in, const int* in_sizes, int n_in,
                              void* d_out, int out_size, void* d_ws, size_t ws_size,
                              hipStream_t stream) {
    const float* x   = (const float*)d_in[0];
    const float* Ws0 = (const float*)d_in[1];
    const float* Wn0 = (const float*)d_in[2];
    const float* Ws1 = (const float*)d_in[3];
    const float* Wn1 = (const float*)d_in[4];
    const float* Ws2 = (const float*)d_in[5];
    const float* Wn2 = (const float*)d_in[6];
    const int* src   = (const int*)d_in[7];
    const int* dst   = (const int*)d_in[8];
    float* out = (float*)d_out;

    char* w = (char*)d_ws;
    size_t off = 0;
    int* row_ptr   = (int*)(w + off);   off += alignup((NN + 1) * 4);
    int* deg       = (int*)(w + off);   off += alignup(NN * 4);
    int* cur       = (int*)(w + off);   off += alignup((size_t)NBUCK * 16 * 4);  // 64B-padded bucket cursors
    int* bsum      = (int*)(w + off);   off += alignup(SCAN_NB * 4);
    int* bb        = (int*)(w + off);   off += alignup((NBUCK + 1) * 4);
    float* inv_deg = (float*)(w + off); off += alignup(NN * 4);
    int* csr       = (int*)(w + off);   off += alignup((size_t)NE * 4);
    unsigned short* wp0 = (unsigned short*)(w + off); off += alignup(8 * 8 * 64 * 8 * 2);
    unsigned short* wp1 = (unsigned short*)(w + off); off += alignup(8 * 8 * 64 * 8 * 2);
    unsigned short* wp2 = (unsigned short*)(w + off); off += alignup(8 * 3 * 64 * 8 * 2);
    unsigned short* hA  = (unsigned short*)(w + off); off += alignup((size_t)NN * 128 * 2);
    unsigned short* hB  = (unsigned short*)(w + off); off += alignup((size_t)NN * 128 * 2);
    unsigned short* agg = (unsigned short*)(w + off); off += alignup((size_t)NN * 128 * 2);
    uint2* pairs = (uint2*)agg;   // alias: pairs (12.8MB) used only before aggregation

    hipMemsetAsync(deg, 0, NN * 4, stream);
    hipMemsetAsync(cur, 0, (size_t)NBUCK * 16 * 4, stream);

    cast_x<<<dim3((NN * 128 / 4 + 255) / 256), dim3(256), 0, stream>>>(x, hA, NN * 128);
    hist_deg<<<dim3(NE / 256), dim3(256), 0, stream>>>(dst, deg);
    scan_partial<<<dim3(SCAN_NB), dim3(SCAN_BS), 0, stream>>>(deg, bsum);
    scan_bsum<<<dim3(1), dim3(256), 0, stream>>>(bsum, SCAN_NB);
    scan_final<<<dim3(SCAN_NB), dim3(SCAN_BS), 0, stream>>>(deg, bsum, row_ptr, inv_deg);
    bb_fill<<<dim3((NBUCK + 256) / 256), dim3(256), 0, stream>>>(row_ptr, bb);
    pair_scatter<<<dim3(NE / 256), dim3(256), 0, stream>>>(src, dst, bb, cur, pairs);
    bucket_place<<<dim3(NBUCK), dim3(256), 0, stream>>>(pairs, row_ptr, bb, csr);

    pack_w<<<dim3((8 * 8 * 64 * 8 + 255) / 256), dim3(256), 0, stream>>>(Ws0, Wn0, wp0, 128, 8);
    pack_w<<<dim3((8 * 8 * 64 * 8 + 255) / 256), dim3(256), 0, stream>>>(Ws1, Wn1, wp1, 128, 8);
    pack_w<<<dim3((8 * 3 * 64 * 8 + 255) / 256), dim3(256), 0, stream>>>(Ws2, Wn2, wp2, 47, 3);

    const int gemmGrid = (NN + 63) / 64;

    // layer 0
    aggregate<<<dim3(NN / 4), dim3(256), 0, stream>>>((const unsigned*)hA, csr, row_ptr, inv_deg, (unsigned*)agg);
    gemm_k<8, false><<<dim3(gemmGrid), dim3(256), 0, stream>>>(hA, agg, wp0, hB, nullptr);
    // layer 1
    aggregate<<<dim3(NN / 4), dim3(256), 0, stream>>>((const unsigned*)hB, csr, row_ptr, inv_deg, (unsigned*)agg);
    gemm_k<8, false><<<dim3(gemmGrid), dim3(256), 0, stream>>>(hB, agg, wp1, hA, nullptr);
    // layer 2
    aggregate<<<dim3(NN / 4), dim3(256), 0, stream>>>((const unsigned*)hA, csr, row_ptr, inv_deg, (unsigned*)agg);
    gemm_k<3, true><<<dim3(gemmGrid), dim3(256), 0, stream>>>(hA, agg, wp2, nullptr, out);
}

// Round 3
// 423.893 us; speedup vs baseline: 1.2101x; 1.1520x over previous
//
#include <hip/hip_runtime.h>
#include <hip/hip_bf16.h>

#define NN 100000
#define NE 1600000
#define SCAN_BS 512
#define SCAN_NB 196   // ceil(100000/512) == bucket count (512 nodes/bucket)
#define SBUCK 196

typedef __attribute__((ext_vector_type(8))) short bf16x8;
typedef __attribute__((ext_vector_type(4))) float f32x4;

__device__ __forceinline__ unsigned short f2bf(float x) {
    unsigned u = __float_as_uint(x);
    return (unsigned short)((u + 0x7fffu + ((u >> 16) & 1u)) >> 16);
}

// ---------------- cast x (f32) -> bf16 ----------------
__global__ void cast_x(const float* __restrict__ x, unsigned short* __restrict__ h, int n) {
    int i = (blockIdx.x * blockDim.x + threadIdx.x) * 4;
    if (i >= n) return;
    float4 v = *(const float4*)(x + i);
    unsigned short o0 = f2bf(v.x), o1 = f2bf(v.y), o2 = f2bf(v.z), o3 = f2bf(v.w);
    unsigned out0 = ((unsigned)o1 << 16) | o0;
    unsigned out1 = ((unsigned)o3 << 16) | o2;
    *(uint2*)(h + i) = make_uint2(out0, out1);
}

// ---------------- degree histogram ----------------
__global__ void hist_deg(const int* __restrict__ dst, int* __restrict__ deg) {
    int e = blockIdx.x * blockDim.x + threadIdx.x;
    if (e < NE) atomicAdd(&deg[dst[e]], 1);
}

// ---------------- scan: block partial sums ----------------
__global__ void scan_partial(const int* __restrict__ deg, int* __restrict__ bsum) {
    __shared__ int s[SCAN_BS];
    int i = blockIdx.x * SCAN_BS + threadIdx.x;
    s[threadIdx.x] = (i < NN) ? deg[i] : 0;
    __syncthreads();
    for (int off = SCAN_BS / 2; off > 0; off >>= 1) {
        if (threadIdx.x < off) s[threadIdx.x] += s[threadIdx.x + off];
        __syncthreads();
    }
    if (threadIdx.x == 0) bsum[blockIdx.x] = s[0];
}

// ------- exclusive scan of block sums; bsum[b] becomes bucket base; init gcur -------
__global__ void scan_bsum(int* __restrict__ bsum, int* __restrict__ gcur, int nb) {
    __shared__ int s[256];
    int t = threadIdx.x;
    int orig = (t < nb) ? bsum[t] : 0;
    s[t] = orig;
    __syncthreads();
    for (int off = 1; off < 256; off <<= 1) {
        int v = (t >= off) ? s[t - off] : 0;
        __syncthreads();
        s[t] += v;
        __syncthreads();
    }
    if (t < nb) {
        int ex = s[t] - orig;
        bsum[t] = ex;
        gcur[t * 16] = ex;   // 64B-padded global bucket cursors, absolute base
    }
}

// ---------------- final scan -> row_ptr (exclusive) + inv_deg ----------------
__global__ void scan_final(const int* __restrict__ deg, const int* __restrict__ bsum,
                           int* __restrict__ row_ptr, float* __restrict__ inv_deg) {
    __shared__ int s[SCAN_BS];
    int i = blockIdx.x * SCAN_BS + threadIdx.x;
    int v = (i < NN) ? deg[i] : 0;
    s[threadIdx.x] = v;
    __syncthreads();
    for (int off = 1; off < SCAN_BS; off <<= 1) {
        int t = (threadIdx.x >= off) ? s[threadIdx.x - off] : 0;
        __syncthreads();
        s[threadIdx.x] += t;
        __syncthreads();
    }
    if (i < NN) {
        int incl = s[threadIdx.x];
        row_ptr[i] = bsum[blockIdx.x] + incl - v;
        inv_deg[i] = 1.0f / (float)max(v, 1);
    }
    if (i == 0) row_ptr[NN] = NE;
}

// ------- phase B: block-local counting sort; contiguous runs per (block,bucket) -------
__global__ __launch_bounds__(256) void sort_scatter(const int* __restrict__ src,
                                                    const int* __restrict__ dst,
                                                    int* __restrict__ gcur,
                                                    unsigned* __restrict__ pairs) {
    __shared__ int bcnt[SBUCK], gbase[SBUCK], lcur[SBUCK];
    int t = threadIdx.x;
    if (t < SBUCK) { bcnt[t] = 0; lcur[t] = 0; }
    __syncthreads();
    int base = blockIdx.x * 4096;
#pragma unroll
    for (int i = 0; i < 16; ++i) {
        int e = base + t + i * 256;
        if (e < NE) atomicAdd(&bcnt[dst[e] >> 9], 1);
    }
    __syncthreads();
    if (t < SBUCK) gbase[t] = atomicAdd(&gcur[t * 16], bcnt[t]);
    __syncthreads();
#pragma unroll
    for (int i = 0; i < 16; ++i) {
        int e = base + t + i * 256;
        if (e < NE) {
            int d = dst[e];
            int b = d >> 9;
            int p = atomicAdd(&lcur[b], 1);
            pairs[gbase[b] + p] = ((unsigned)src[e] << 9) | (unsigned)(d & 511);
        }
    }
}

// ------- phase C: one block per bucket; scatter within 32KB csr window -------
__global__ __launch_bounds__(512) void bucket_place(const unsigned* __restrict__ pairs,
                                                    const int* __restrict__ row_ptr,
                                                    const int* __restrict__ bsum,
                                                    int* __restrict__ csr) {
    __shared__ int curs[512];
    int b = blockIdx.x;
    int base = b * 512;
    if (threadIdx.x < 512) curs[threadIdx.x] = row_ptr[min(base + (int)threadIdx.x, NN)];
    __syncthreads();
    int beg = bsum[b];
    int end = (b == SBUCK - 1) ? NE : bsum[b + 1];
    for (int i = beg + (int)threadIdx.x; i < end; i += 512) {
        unsigned p = pairs[i];
        int pos = atomicAdd(&curs[p & 511u], 1);
        csr[pos] = (int)(p >> 9);
    }
}

// ---------------- pack [W_self; W_neigh] (f32) into MFMA B-fragment bf16 layout ----------------
__global__ void pack_w(const float* __restrict__ Wself, const float* __restrict__ Wneigh,
                       unsigned short* __restrict__ wpack, int Ncols, int NF) {
    int idx = blockIdx.x * blockDim.x + threadIdx.x;
    int total = 8 * NF * 64 * 8;
    if (idx >= total) return;
    int j = idx & 7;
    int lane = (idx >> 3) & 63;
    int fid = idx >> 9;          // kstep*NF + nf
    int nf = fid % NF;
    int kstep = fid / NF;
    int k = kstep * 32 + (lane >> 4) * 8 + j;
    int n = nf * 16 + (lane & 15);
    float v = 0.f;
    if (n < Ncols) v = (k < 128) ? Wself[k * Ncols + n] : Wneigh[(k - 128) * Ncols + n];
    wpack[idx] = f2bf(v);
}

// ---------------- pull-mode mean aggregation: one wave per node ----------------
__global__ void aggregate(const unsigned* __restrict__ h32, const int* __restrict__ csr,
                          const int* __restrict__ row_ptr, const float* __restrict__ inv_deg,
                          unsigned* __restrict__ agg32) {
    int lane = threadIdx.x & 63;
    int node = blockIdx.x * (blockDim.x >> 6) + (threadIdx.x >> 6);
    if (node >= NN) return;
    int beg = row_ptr[node], end = row_ptr[node + 1];
    float a0 = 0.f, a1 = 0.f;
    int e = beg;
    for (; e + 3 < end; e += 4) {
        int s0 = csr[e], s1 = csr[e + 1], s2 = csr[e + 2], s3 = csr[e + 3];
        unsigned v0 = h32[s0 * 64 + lane];
        unsigned v1 = h32[s1 * 64 + lane];
        unsigned v2 = h32[s2 * 64 + lane];
        unsigned v3 = h32[s3 * 64 + lane];
        a0 += __uint_as_float(v0 << 16) + __uint_as_float(v1 << 16)
            + __uint_as_float(v2 << 16) + __uint_as_float(v3 << 16);
        a1 += __uint_as_float(v0 & 0xffff0000u) + __uint_as_float(v1 & 0xffff0000u)
            + __uint_as_float(v2 & 0xffff0000u) + __uint_as_float(v3 & 0xffff0000u);
    }
    for (; e < end; ++e) {
        unsigned v = h32[csr[e] * 64 + lane];
        a0 += __uint_as_float(v << 16);
        a1 += __uint_as_float(v & 0xffff0000u);
    }
    float inv = inv_deg[node];
    a0 *= inv; a1 *= inv;
    agg32[node * 64 + lane] = ((unsigned)f2bf(a1) << 16) | f2bf(a0);
}

// ---------------- fused GEMM: out = h@Wself + agg@Wneigh (K=256 via packed W) ----------------
template <int NF, bool LAST>
__global__ __launch_bounds__(256) void gemm_k(const unsigned short* __restrict__ hA,
                                              const unsigned short* __restrict__ hAgg,
                                              const unsigned short* __restrict__ wpack,
                                              unsigned short* __restrict__ hOut,
                                              float* __restrict__ fOut) {
    int lane = threadIdx.x & 63;
    int wave = threadIdx.x >> 6;
    int aRow = blockIdx.x * 64 + wave * 16 + (lane & 15);
    int kgrp = (lane >> 4) * 8;

    f32x4 acc[NF];
#pragma unroll
    for (int f = 0; f < NF; ++f)
#pragma unroll
        for (int r = 0; r < 4; ++r) acc[f][r] = 0.f;

    bool inb = (aRow < NN);
#pragma unroll
    for (int half = 0; half < 2; ++half) {
        const unsigned short* A = half ? hAgg : hA;
#pragma unroll
        for (int ks = 0; ks < 4; ++ks) {
            bf16x8 afrag;
            if (inb) {
                afrag = *(const bf16x8*)(A + aRow * 128 + ks * 32 + kgrp);
            } else {
#pragma unroll
                for (int j = 0; j < 8; ++j) afrag[j] = 0;
            }
            int kstep = half * 4 + ks;
#pragma unroll
            for (int nf = 0; nf < NF; ++nf) {
                bf16x8 b = *(const bf16x8*)(wpack + (((kstep * NF + nf) * 64) + lane) * 8);
                acc[nf] = __builtin_amdgcn_mfma_f32_16x16x32_bf16(afrag, b, acc[nf], 0, 0, 0);
            }
        }
    }

    int col0 = lane & 15;
    int rBase = blockIdx.x * 64 + wave * 16 + (lane >> 4) * 4;
#pragma unroll
    for (int nf = 0; nf < NF; ++nf) {
        int col = nf * 16 + col0;
        if (LAST) {
            if (col < 47) {
#pragma unroll
                for (int r = 0; r < 4; ++r) {
                    int row = rBase + r;
                    if (row < NN) fOut[row * 47 + col] = acc[nf][r];
                }
            }
        } else {
#pragma unroll
            for (int r = 0; r < 4; ++r) {
                int row = rBase + r;
                if (row < NN) hOut[row * 128 + col] = f2bf(fmaxf(acc[nf][r], 0.f));
            }
        }
    }
}

static inline size_t alignup(size_t x) { return (x + 255) & ~(size_t)255; }

extern "C" void kernel_launch(void* const* d_in, const int* in_sizes, int n_in,
                              void* d_out, int out_size, void* d_ws, size_t ws_size,
                              hipStream_t stream) {
    const float* x   = (const float*)d_in[0];
    const float* Ws0 = (const float*)d_in[1];
    const float* Wn0 = (const float*)d_in[2];
    const float* Ws1 = (const float*)d_in[3];
    const float* Wn1 = (const float*)d_in[4];
    const float* Ws2 = (const float*)d_in[5];
    const float* Wn2 = (const float*)d_in[6];
    const int* src   = (const int*)d_in[7];
    const int* dst   = (const int*)d_in[8];
    float* out = (float*)d_out;

    char* w = (char*)d_ws;
    size_t off = 0;
    int* row_ptr   = (int*)(w + off);   off += alignup((NN + 1) * 4);
    int* deg       = (int*)(w + off);   off += alignup(NN * 4);
    int* gcur      = (int*)(w + off);   off += alignup((size_t)SBUCK * 16 * 4);
    int* bsum      = (int*)(w + off);   off += alignup(SCAN_NB * 4);
    float* inv_deg = (float*)(w + off); off += alignup(NN * 4);
    int* csr       = (int*)(w + off);   off += alignup((size_t)NE * 4);
    unsigned short* wp0 = (unsigned short*)(w + off); off += alignup(8 * 8 * 64 * 8 * 2);
    unsigned short* wp1 = (unsigned short*)(w + off); off += alignup(8 * 8 * 64 * 8 * 2);
    unsigned short* wp2 = (unsigned short*)(w + off); off += alignup(8 * 3 * 64 * 8 * 2);
    unsigned short* hA  = (unsigned short*)(w + off); off += alignup((size_t)NN * 128 * 2);
    unsigned short* hB  = (unsigned short*)(w + off); off += alignup((size_t)NN * 128 * 2);
    unsigned short* agg = (unsigned short*)(w + off); off += alignup((size_t)NN * 128 * 2);
    unsigned* pairs = (unsigned*)agg;   // alias: packed pairs (6.4MB) used only before aggregation

    hipMemsetAsync(deg, 0, NN * 4, stream);

    cast_x<<<dim3((NN * 128 / 4 + 255) / 256), dim3(256), 0, stream>>>(x, hA, NN * 128);
    hist_deg<<<dim3(NE / 256), dim3(256), 0, stream>>>(dst, deg);
    scan_partial<<<dim3(SCAN_NB), dim3(SCAN_BS), 0, stream>>>(deg, bsum);
    scan_bsum<<<dim3(1), dim3(256), 0, stream>>>(bsum, gcur, SCAN_NB);
    scan_final<<<dim3(SCAN_NB), dim3(SCAN_BS), 0, stream>>>(deg, bsum, row_ptr, inv_deg);
    sort_scatter<<<dim3((NE + 4095) / 4096), dim3(256), 0, stream>>>(src, dst, gcur, pairs);
    bucket_place<<<dim3(SBUCK), dim3(512), 0, stream>>>(pairs, row_ptr, bsum, csr);

    pack_w<<<dim3((8 * 8 * 64 * 8 + 255) / 256), dim3(256), 0, stream>>>(Ws0, Wn0, wp0, 128, 8);
    pack_w<<<dim3((8 * 8 * 64 * 8 + 255) / 256), dim3(256), 0, stream>>>(Ws1, Wn1, wp1, 128, 8);
    pack_w<<<dim3((8 * 3 * 64 * 8 + 255) / 256), dim3(256), 0, stream>>>(Ws2, Wn2, wp2, 47, 3);

    const int gemmGrid = (NN + 63) / 64;

    // layer 0
    aggregate<<<dim3(NN / 4), dim3(256), 0, stream>>>((const unsigned*)hA, csr, row_ptr, inv_deg, (unsigned*)agg);
    gemm_k<8, false><<<dim3(gemmGrid), dim3(256), 0, stream>>>(hA, agg, wp0, hB, nullptr);
    // layer 1
    aggregate<<<dim3(NN / 4), dim3(256), 0, stream>>>((const unsigned*)hB, csr, row_ptr, inv_deg, (unsigned*)agg);
    gemm_k<8, false><<<dim3(gemmGrid), dim3(256), 0, stream>>>(hB, agg, wp1, hA, nullptr);
    // layer 2
    aggregate<<<dim3(NN / 4), dim3(256), 0, stream>>>((const unsigned*)hA, csr, row_ptr, inv_deg, (unsigned*)agg);
    gemm_k<3, true><<<dim3(gemmGrid), dim3(256), 0, stream>>>(hA, agg, wp2, nullptr, out);
}

// Round 4
// 340.602 us; speedup vs baseline: 1.5061x; 1.2445x over previous
//
#include <hip/hip_runtime.h>
#include <hip/hip_bf16.h>

#define NN 100000
#define NE 1600000
#define NBK 196          // buckets of 512 nodes: ceil(100000/512)

typedef __attribute__((ext_vector_type(8))) short bf16x8;
typedef __attribute__((ext_vector_type(4))) float f32x4;

__device__ __forceinline__ unsigned short f2bf(float x) {
    unsigned u = __float_as_uint(x);
    return (unsigned short)((u + 0x7fffu + ((u >> 16) & 1u)) >> 16);
}
__device__ __forceinline__ float bflo(unsigned v) { return __uint_as_float(v << 16); }
__device__ __forceinline__ float bfhi(unsigned v) { return __uint_as_float(v & 0xffff0000u); }

// ---------------- cast x (f32) -> bf16 ----------------
__global__ void cast_x(const float* __restrict__ x, unsigned short* __restrict__ h, int n) {
    int i = (blockIdx.x * blockDim.x + threadIdx.x) * 4;
    if (i >= n) return;
    float4 v = *(const float4*)(x + i);
    unsigned out0 = ((unsigned)f2bf(v.y) << 16) | f2bf(v.x);
    unsigned out1 = ((unsigned)f2bf(v.w) << 16) | f2bf(v.z);
    *(uint2*)(h + i) = make_uint2(out0, out1);
}

// ---------------- bucket histogram (196 buckets, LDS-first) ----------------
__global__ __launch_bounds__(256) void hist_buck(const int* __restrict__ dst, int* __restrict__ bhist) {
    __shared__ int h[NBK];
    int t = threadIdx.x;
    if (t < NBK) h[t] = 0;
    __syncthreads();
    int base = blockIdx.x * 4096;
#pragma unroll
    for (int i = 0; i < 16; ++i) {
        int e = base + t + i * 256;
        if (e < NE) atomicAdd(&h[dst[e] >> 9], 1);
    }
    __syncthreads();
    if (t < NBK && h[t]) atomicAdd(&bhist[t], h[t]);
}

// ------- scan buckets -> bbase (exclusive, bbase[NBK]=NE) + init gcur + row_ptr[NN] -------
__global__ void scan_buck(const int* __restrict__ bhist, int* __restrict__ bbase,
                          int* __restrict__ gcur, int* __restrict__ row_ptr) {
    __shared__ int s[256];
    int t = threadIdx.x;
    int v = (t < NBK) ? bhist[t] : 0;
    s[t] = v;
    __syncthreads();
    for (int off = 1; off < 256; off <<= 1) {
        int u = (t >= off) ? s[t - off] : 0;
        __syncthreads();
        s[t] += u;
        __syncthreads();
    }
    int ex = s[t] - v;
    if (t <= NBK) bbase[t] = ex;          // bbase[NBK] == NE
    if (t < NBK) gcur[t * 16] = ex;
    if (t == 0) row_ptr[NN] = NE;
}

// ------- block-local counting sort; contiguous runs per (block,bucket) -------
__global__ __launch_bounds__(256) void sort_scatter(const int* __restrict__ src,
                                                    const int* __restrict__ dst,
                                                    int* __restrict__ gcur,
                                                    unsigned* __restrict__ pairs) {
    __shared__ int bcnt[NBK], gbase[NBK], lcur[NBK];
    int t = threadIdx.x;
    if (t < NBK) { bcnt[t] = 0; lcur[t] = 0; }
    __syncthreads();
    int base = blockIdx.x * 4096;
#pragma unroll
    for (int i = 0; i < 16; ++i) {
        int e = base + t + i * 256;
        if (e < NE) atomicAdd(&bcnt[dst[e] >> 9], 1);
    }
    __syncthreads();
    if (t < NBK) gbase[t] = atomicAdd(&gcur[t * 16], bcnt[t]);
    __syncthreads();
#pragma unroll
    for (int i = 0; i < 16; ++i) {
        int e = base + t + i * 256;
        if (e < NE) {
            int d = dst[e];
            int b = d >> 9;
            int p = atomicAdd(&lcur[b], 1);
            pairs[gbase[b] + p] = ((unsigned)src[e] << 9) | (unsigned)(d & 511);
        }
    }
}

// ------- per bucket: node hist + scan -> row_ptr/inv_deg, then place edges -> csr -------
__global__ __launch_bounds__(512) void bucket_place(const unsigned* __restrict__ pairs,
                                                    const int* __restrict__ bbase,
                                                    int* __restrict__ row_ptr,
                                                    float* __restrict__ inv_deg,
                                                    int* __restrict__ csr) {
    __shared__ int hist[512], sc[512], cur[512];
    int b = blockIdx.x, t = threadIdx.x;
    hist[t] = 0;
    __syncthreads();
    int beg = bbase[b], end = bbase[b + 1];
    for (int i = beg + t; i < end; i += 512) atomicAdd(&hist[pairs[i] & 511u], 1);
    __syncthreads();
    int deg = hist[t];
    sc[t] = deg;
    __syncthreads();
    for (int off = 1; off < 512; off <<= 1) {
        int u = (t >= off) ? sc[t - off] : 0;
        __syncthreads();
        sc[t] += u;
        __syncthreads();
    }
    int ex = sc[t] - deg;
    int node = b * 512 + t;
    if (node < NN) {
        row_ptr[node] = beg + ex;
        inv_deg[node] = 1.0f / (float)max(deg, 1);
    }
    cur[t] = beg + ex;
    __syncthreads();
    for (int i = beg + t; i < end; i += 512) {
        unsigned p = pairs[i];
        int pos = atomicAdd(&cur[p & 511u], 1);
        csr[pos] = (int)(p >> 9);
    }
}

// ---------------- pack [W_self; W_neigh] (f32) into MFMA B-fragment bf16 layout ----------------
__global__ void pack_w(const float* __restrict__ Wself, const float* __restrict__ Wneigh,
                       unsigned short* __restrict__ wpack, int Ncols, int NF) {
    int idx = blockIdx.x * blockDim.x + threadIdx.x;
    int total = 8 * NF * 64 * 8;
    if (idx >= total) return;
    int j = idx & 7;
    int lane = (idx >> 3) & 63;
    int fid = idx >> 9;          // kstep*NF + nf
    int nf = fid % NF;
    int kstep = fid / NF;
    int k = kstep * 32 + (lane >> 4) * 8 + j;
    int n = nf * 16 + (lane & 15);
    float v = 0.f;
    if (n < Ncols) v = (k < 128) ? Wself[k * Ncols + n] : Wneigh[(k - 128) * Ncols + n];
    wpack[idx] = f2bf(v);
}

// ---------------- pull-mode mean aggregation: one wave per node, 8 rows in flight ----------------
__global__ void aggregate(const unsigned* __restrict__ h32, const int* __restrict__ csr,
                          const int* __restrict__ row_ptr, const float* __restrict__ inv_deg,
                          unsigned* __restrict__ agg32) {
    int lane = threadIdx.x & 63;
    int node = blockIdx.x * (blockDim.x >> 6) + (threadIdx.x >> 6);
    if (node >= NN) return;
    int beg = row_ptr[node], end = row_ptr[node + 1];
    float a0 = 0.f, a1 = 0.f, b0 = 0.f, b1 = 0.f;
    int e = beg;
    for (; e + 7 < end; e += 8) {
        int s0 = csr[e], s1 = csr[e + 1], s2 = csr[e + 2], s3 = csr[e + 3];
        int s4 = csr[e + 4], s5 = csr[e + 5], s6 = csr[e + 6], s7 = csr[e + 7];
        unsigned v0 = h32[s0 * 64 + lane];
        unsigned v1 = h32[s1 * 64 + lane];
        unsigned v2 = h32[s2 * 64 + lane];
        unsigned v3 = h32[s3 * 64 + lane];
        unsigned v4 = h32[s4 * 64 + lane];
        unsigned v5 = h32[s5 * 64 + lane];
        unsigned v6 = h32[s6 * 64 + lane];
        unsigned v7 = h32[s7 * 64 + lane];
        a0 += bflo(v0) + bflo(v1) + bflo(v2) + bflo(v3);
        a1 += bfhi(v0) + bfhi(v1) + bfhi(v2) + bfhi(v3);
        b0 += bflo(v4) + bflo(v5) + bflo(v6) + bflo(v7);
        b1 += bfhi(v4) + bfhi(v5) + bfhi(v6) + bfhi(v7);
    }
    for (; e + 3 < end; e += 4) {
        int s0 = csr[e], s1 = csr[e + 1], s2 = csr[e + 2], s3 = csr[e + 3];
        unsigned v0 = h32[s0 * 64 + lane];
        unsigned v1 = h32[s1 * 64 + lane];
        unsigned v2 = h32[s2 * 64 + lane];
        unsigned v3 = h32[s3 * 64 + lane];
        a0 += bflo(v0) + bflo(v1) + bflo(v2) + bflo(v3);
        a1 += bfhi(v0) + bfhi(v1) + bfhi(v2) + bfhi(v3);
    }
    for (; e < end; ++e) {
        unsigned v = h32[csr[e] * 64 + lane];
        a0 += bflo(v);
        a1 += bfhi(v);
    }
    a0 += b0; a1 += b1;
    float inv = inv_deg[node];
    a0 *= inv; a1 *= inv;
    agg32[node * 64 + lane] = ((unsigned)f2bf(a1) << 16) | f2bf(a0);
}

// ---------------- fused GEMM: out = h@Wself + agg@Wneigh (K=256 via packed W) ----------------
template <int NF, bool LAST>
__global__ __launch_bounds__(256) void gemm_k(const unsigned short* __restrict__ hA,
                                              const unsigned short* __restrict__ hAgg,
                                              const unsigned short* __restrict__ wpack,
                                              unsigned short* __restrict__ hOut,
                                              float* __restrict__ fOut) {
    int lane = threadIdx.x & 63;
    int wave = threadIdx.x >> 6;
    int aRow = blockIdx.x * 64 + wave * 16 + (lane & 15);
    int kgrp = (lane >> 4) * 8;

    f32x4 acc[NF];
#pragma unroll
    for (int f = 0; f < NF; ++f)
#pragma unroll
        for (int r = 0; r < 4; ++r) acc[f][r] = 0.f;

    bool inb = (aRow < NN);
#pragma unroll
    for (int half = 0; half < 2; ++half) {
        const unsigned short* A = half ? hAgg : hA;
#pragma unroll
        for (int ks = 0; ks < 4; ++ks) {
            bf16x8 afrag;
            if (inb) {
                afrag = *(const bf16x8*)(A + aRow * 128 + ks * 32 + kgrp);
            } else {
#pragma unroll
                for (int j = 0; j < 8; ++j) afrag[j] = 0;
            }
            int kstep = half * 4 + ks;
#pragma unroll
            for (int nf = 0; nf < NF; ++nf) {
                bf16x8 b = *(const bf16x8*)(wpack + (((kstep * NF + nf) * 64) + lane) * 8);
                acc[nf] = __builtin_amdgcn_mfma_f32_16x16x32_bf16(afrag, b, acc[nf], 0, 0, 0);
            }
        }
    }

    int col0 = lane & 15;
    int rBase = blockIdx.x * 64 + wave * 16 + (lane >> 4) * 4;
#pragma unroll
    for (int nf = 0; nf < NF; ++nf) {
        int col = nf * 16 + col0;
        if (LAST) {
            if (col < 47) {
#pragma unroll
                for (int r = 0; r < 4; ++r) {
                    int row = rBase + r;
                    if (row < NN) fOut[row * 47 + col] = acc[nf][r];
                }
            }
        } else {
#pragma unroll
            for (int r = 0; r < 4; ++r) {
                int row = rBase + r;
                if (row < NN) hOut[row * 128 + col] = f2bf(fmaxf(acc[nf][r], 0.f));
            }
        }
    }
}

static inline size_t alignup(size_t x) { return (x + 255) & ~(size_t)255; }

extern "C" void kernel_launch(void* const* d_in, const int* in_sizes, int n_in,
                              void* d_out, int out_size, void* d_ws, size_t ws_size,
                              hipStream_t stream) {
    const float* x   = (const float*)d_in[0];
    const float* Ws0 = (const float*)d_in[1];
    const float* Wn0 = (const float*)d_in[2];
    const float* Ws1 = (const float*)d_in[3];
    const float* Wn1 = (const float*)d_in[4];
    const float* Ws2 = (const float*)d_in[5];
    const float* Wn2 = (const float*)d_in[6];
    const int* src   = (const int*)d_in[7];
    const int* dst   = (const int*)d_in[8];
    float* out = (float*)d_out;

    char* w = (char*)d_ws;
    size_t off = 0;
    int* row_ptr   = (int*)(w + off);   off += alignup((NN + 1) * 4);
    int* bhist     = (int*)(w + off);   off += alignup(NBK * 4);
    int* bbase     = (int*)(w + off);   off += alignup((NBK + 1) * 4);
    int* gcur      = (int*)(w + off);   off += alignup((size_t)NBK * 16 * 4);
    float* inv_deg = (float*)(w + off); off += alignup(NN * 4);
    int* csr       = (int*)(w + off);   off += alignup((size_t)NE * 4);
    unsigned short* wp0 = (unsigned short*)(w + off); off += alignup(8 * 8 * 64 * 8 * 2);
    unsigned short* wp1 = (unsigned short*)(w + off); off += alignup(8 * 8 * 64 * 8 * 2);
    unsigned short* wp2 = (unsigned short*)(w + off); off += alignup(8 * 3 * 64 * 8 * 2);
    unsigned short* hA  = (unsigned short*)(w + off); off += alignup((size_t)NN * 128 * 2);
    unsigned short* hB  = (unsigned short*)(w + off); off += alignup((size_t)NN * 128 * 2);
    unsigned short* agg = (unsigned short*)(w + off); off += alignup((size_t)NN * 128 * 2);
    unsigned* pairs = (unsigned*)agg;   // alias: packed pairs (6.4MB) used only before aggregation

    hipMemsetAsync(bhist, 0, NBK * 4, stream);

    cast_x<<<dim3((NN * 128 / 4 + 255) / 256), dim3(256), 0, stream>>>(x, hA, NN * 128);
    hist_buck<<<dim3((NE + 4095) / 4096), dim3(256), 0, stream>>>(dst, bhist);
    scan_buck<<<dim3(1), dim3(256), 0, stream>>>(bhist, bbase, gcur, row_ptr);
    sort_scatter<<<dim3((NE + 4095) / 4096), dim3(256), 0, stream>>>(src, dst, gcur, pairs);
    bucket_place<<<dim3(NBK), dim3(512), 0, stream>>>(pairs, bbase, row_ptr, inv_deg, csr);

    pack_w<<<dim3((8 * 8 * 64 * 8 + 255) / 256), dim3(256), 0, stream>>>(Ws0, Wn0, wp0, 128, 8);
    pack_w<<<dim3((8 * 8 * 64 * 8 + 255) / 256), dim3(256), 0, stream>>>(Ws1, Wn1, wp1, 128, 8);
    pack_w<<<dim3((8 * 3 * 64 * 8 + 255) / 256), dim3(256), 0, stream>>>(Ws2, Wn2, wp2, 47, 3);

    const int gemmGrid = (NN + 63) / 64;

    // layer 0
    aggregate<<<dim3(NN / 4), dim3(256), 0, stream>>>((const unsigned*)hA, csr, row_ptr, inv_deg, (unsigned*)agg);
    gemm_k<8, false><<<dim3(gemmGrid), dim3(256), 0, stream>>>(hA, agg, wp0, hB, nullptr);
    // layer 1
    aggregate<<<dim3(NN / 4), dim3(256), 0, stream>>>((const unsigned*)hB, csr, row_ptr, inv_deg, (unsigned*)agg);
    gemm_k<8, false><<<dim3(gemmGrid), dim3(256), 0, stream>>>(hB, agg, wp1, hA, nullptr);
    // layer 2
    aggregate<<<dim3(NN / 4), dim3(256), 0, stream>>>((const unsigned*)hA, csr, row_ptr, inv_deg, (unsigned*)agg);
    gemm_k<3, true><<<dim3(gemmGrid), dim3(256), 0, stream>>>(hA, agg, wp2, nullptr, out);
}